// Round 1
// baseline (247.250 us; speedup 1.0000x reference)
//
#include <hip/hip_runtime.h>
#include <math.h>

namespace {

constexpr int Himg = 224, Wimg = 224, Cn = 3, Kk = 32;

__global__ __launch_bounds__(256)
void blur_fused(const float* __restrict__ x,
                const float* __restrict__ tbl,
                const int* __restrict__ amt,
                const int* __restrict__ ang,
                float* __restrict__ out)
{
    const int b   = blockIdx.z;
    const int tid = threadIdx.x;

    __shared__ int            s_count;
    __shared__ float          s_w;
    __shared__ unsigned short s_taps[Kk * Kk];

    if (tid == 0) { s_count = 0; s_w = 0.0f; }
    __syncthreads();

    // ---- build rotated-kernel tap list (matches reference numerics) ----
    const int a = amt[b];
    // rad = float32(angle) * float32(pi/180)
    const float rad = (float)ang[b] * (float)(M_PI / 180.0);
    // correctly-rounded f32 sin/cos of the f32 radian
    const double rd  = (double)rad;
    const float  cth = (float)cos(rd);
    const float  sth = (float)sin(rd);
    const float  e   = 31.0f;
    // x_off = (e - (cos*e - sin*e)) * 0.5 ; y_off = (e - (sin*e + cos*e)) * 0.5
    // strict f32, exact source expression order, no fma contraction
    const float xoff = __fmul_rn(__fsub_rn(e, __fsub_rn(__fmul_rn(cth, e), __fmul_rn(sth, e))), 0.5f);
    const float yoff = __fmul_rn(__fsub_rn(e, __fadd_rn(__fmul_rn(sth, e), __fmul_rn(cth, e))), 0.5f);

    for (int p = tid; p < Kk * Kk; p += 256) {
        const int   ky = p >> 5, kx = p & 31;
        const float xf = (float)kx, yf = (float)ky;
        // sx = cos*xx - sin*yy + x_off ; sy = sin*xx + cos*yy + y_off
        const float sx = __fadd_rn(__fsub_rn(__fmul_rn(cth, xf), __fmul_rn(sth, yf)), xoff);
        const float sy = __fadd_rn(__fadd_rn(__fmul_rn(sth, xf), __fmul_rn(cth, yf)), yoff);
        const int ix = (int)rintf(sx);   // rintf = round-half-even, matches jnp.round
        const int iy = (int)rintf(sy);
        if (ix >= 0 && ix < Kk && iy >= 0 && iy < Kk) {
            const float v = tbl[((size_t)(a * Kk + iy) * Kk + ix) * Cn];  // channel 0 (all equal)
            if (v != 0.0f) {
                const int idx = atomicAdd(&s_count, 1);
                s_taps[idx] = (unsigned short)p;  // packed (ky<<5)|kx
                s_w = v;                          // benign race: all writers store 1/size
            }
        }
    }
    __syncthreads();

    const int   n = s_count;
    const float w = s_w;

    // ---- depthwise conv over sparse taps, SAME zero padding ----
    const int oy = (blockIdx.y << 4) + (tid >> 4);
    const int ox = (blockIdx.x << 4) + (tid & 15);

    float a0 = 0.0f, a1 = 0.0f, a2 = 0.0f;
    const float* xb = x + (size_t)b * (Himg * Wimg * Cn);
    for (int i = 0; i < n; ++i) {
        const int pk = s_taps[i];
        const int yy = oy + (pk >> 5) - 15;   // ky - pad_top(15)
        const int xx = ox + (pk & 31) - 15;   // kx - pad_left(15)
        if ((unsigned)yy < (unsigned)Himg && (unsigned)xx < (unsigned)Wimg) {
            const float* p = xb + ((size_t)yy * Wimg + xx) * Cn;
            a0 += p[0]; a1 += p[1]; a2 += p[2];
        }
    }

    float* o = out + ((size_t)b * Himg * Wimg + (size_t)oy * Wimg + ox) * Cn;
    o[0] = a0 * w;
    o[1] = a1 * w;
    o[2] = a2 * w;
}

}  // namespace

extern "C" void kernel_launch(void* const* d_in, const int* in_sizes, int n_in,
                              void* d_out, int out_size, void* d_ws, size_t ws_size,
                              hipStream_t stream) {
    const float* x   = (const float*)d_in[0];
    const float* tbl = (const float*)d_in[1];
    const int*   amt = (const int*)d_in[2];
    const int*   ang = (const int*)d_in[3];
    float*       out = (float*)d_out;

    const int B = in_sizes[2];  // 128
    dim3 grid(Wimg / 16, Himg / 16, B);
    blur_fused<<<grid, 256, 0, stream>>>(x, tbl, amt, ang, out);
}